// Round 1
// baseline (88.684 us; speedup 1.0000x reference)
//
#include <hip/hip_runtime.h>
#include <cmath>

// Problem constants (from reference): B=32, N=8192, C=16, K=4
constexpr int Bn = 32, Nn = 8192, Cn = 16, Kn = 4;
constexpr float EPSF   = 1e-8f;
constexpr float NEGINF = -1e9f;

constexpr int NSPLIT = 16;               // N-chunks per batch -> 512 blocks total
constexpr int CHUNK  = Nn / NSPLIT;      // 512 n's per block
constexpr int ITERS  = CHUNK / 16;       // 32 iters per thread (16 n_sub lanes)
constexpr int PART   = 10;               // floats per (c,k) partial: S1..S4,W,mx,sx,mn,sn,ne
constexpr int BLOCK_WS = Cn * Kn * PART; // 640 floats per block partial

__device__ __forceinline__ void lse_push(float u, float& m, float& s) {
  // online logsumexp accumulate of one element u
  if (u > m) { s = s * __expf(m - u) + 1.0f; m = u; }
  else       { s += __expf(u - m); }
}
__device__ __forceinline__ void lse_merge(float mi, float si, float& m, float& s) {
  if (mi > m) { s = s * __expf(m - mi) + si; m = mi; }
  else        { s += si * __expf(mi - m); }
}

// Kernel 1: per (b, n-chunk) block computes raw-moment partials per (c,k)
// thread t = n_sub*16 + c  (c in low 4 bits -> coalesced values loads:
// a wave's 64 lanes cover 4 consecutive n x 16 c = 256B contiguous)
__global__ __launch_bounds__(256) void stats_partial(
    const float* __restrict__ values, const float* __restrict__ mask,
    const float* __restrict__ weights, float* __restrict__ ws)
{
  const int blk  = blockIdx.x;
  const int b    = blk / NSPLIT;
  const int n0   = (blk % NSPLIT) * CHUNK;
  const int t    = threadIdx.x;
  const int nsub = t >> 4;
  const int c    = t & 15;

  float S[4][4];                 // [power p][k]
  float W[4];
  #pragma unroll
  for (int k = 0; k < 4; ++k) {
    W[k] = 0.f;
    #pragma unroll
    for (int p = 0; p < 4; ++p) S[p][k] = 0.f;
  }
  float mx = NEGINF, sx = 0.f;   // lse over masked v    (-> max_soft)
  float mnv = NEGINF, sn = 0.f;  // lse over masked -v   (-> min_soft)
  float ne = 0.f;                // mask sum partial

  const float*  vb = values + ((size_t)b * Nn) * Cn + c;
  const float*  mb = mask + (size_t)b * Nn;
  const float4* wb = reinterpret_cast<const float4*>(weights + ((size_t)b * Nn) * Kn);

  #pragma unroll 4
  for (int i = 0; i < ITERS; ++i) {
    const int n = n0 + i * 16 + nsub;
    const float v   = vb[(size_t)n * Cn];
    const float mk  = mb[n];
    const float4 w4 = wb[n];
    const float v2 = v * v, v3 = v2 * v, v4q = v2 * v2;
    const float wm[4] = {w4.x * mk, w4.y * mk, w4.z * mk, w4.w * mk};
    #pragma unroll
    for (int k = 0; k < 4; ++k) {
      W[k]    += wm[k];
      S[0][k] += wm[k] * v;
      S[1][k] += wm[k] * v2;
      S[2][k] += wm[k] * v3;
      S[3][k] += wm[k] * v4q;
    }
    ne += mk;
    const bool on = (mk != 0.f);
    lse_push(on ?  v : NEGINF, mx,  sx);
    lse_push(on ? -v : NEGINF, mnv, sn);
  }

  // Block reduction over the 16 n_sub lanes per c
  __shared__ float red[256][27];   // 27 = 25 used + pad (odd stride, bank-friendly)
  {
    float* r = red[t];
    #pragma unroll
    for (int p = 0; p < 4; ++p)
      #pragma unroll
      for (int k = 0; k < 4; ++k) r[p * 4 + k] = S[p][k];
    #pragma unroll
    for (int k = 0; k < 4; ++k) r[16 + k] = W[k];
    r[20] = mx; r[21] = sx; r[22] = mnv; r[23] = sn; r[24] = ne;
  }
  __syncthreads();

  if (t < 64) {                      // one thread per (c,k)
    const int cc = t >> 2, k = t & 3;
    float tS[4] = {0.f, 0.f, 0.f, 0.f};
    float tW = 0.f, tne = 0.f;
    float tmx = NEGINF, tsx = 0.f, tmn = NEGINF, tsn = 0.f;
    for (int ns = 0; ns < 16; ++ns) {
      const float* q = red[ns * 16 + cc];
      #pragma unroll
      for (int p = 0; p < 4; ++p) tS[p] += q[p * 4 + k];
      tW += q[16 + k];
      lse_merge(q[20], q[21], tmx, tsx);
      lse_merge(q[22], q[23], tmn, tsn);
      tne += q[24];                  // identical across c for a given nsub row
    }
    float* o = ws + (size_t)blk * BLOCK_WS + (size_t)t * PART;
    o[0] = tS[0]; o[1] = tS[1]; o[2] = tS[2]; o[3] = tS[3];
    o[4] = tW; o[5] = tmx; o[6] = tsx; o[7] = tmn; o[8] = tsn; o[9] = tne;
  }
}

// Kernel 2: merge NSPLIT chunk-partials per (b,c,k), compute the 19 stats
__global__ __launch_bounds__(64) void stats_final(
    const float* __restrict__ ws, float* __restrict__ out)
{
  const int b = blockIdx.x;
  const int t = threadIdx.x;       // (c,k) = (t>>2, t&3)
  float S0 = 0.f, S1 = 0.f, S2 = 0.f, S3 = 0.f, W = 0.f, ne = 0.f;
  float mx = NEGINF, sx = 0.f, mnv = NEGINF, sn = 0.f;
  for (int ch = 0; ch < NSPLIT; ++ch) {
    const float* p = ws + ((size_t)(b * NSPLIT + ch)) * BLOCK_WS + (size_t)t * PART;
    S0 += p[0]; S1 += p[1]; S2 += p[2]; S3 += p[3]; W += p[4];
    lse_merge(p[5], p[6], mx, sx);
    lse_merge(p[7], p[8], mnv, sn);
    ne += p[9];
  }
  const float denom = W + EPSF;
  const float mom1 = S0 / denom, mom2 = S1 / denom, mom3 = S2 / denom, mom4 = S3 / denom;
  const float mean = mom1;
  const float me2  = mean * mean;
  // central moments via raw-moment expansion (mask is binary; w_norm already masked)
  const float var  = mom2 - me2;
  const float m3   = mom3 - 3.f * mean * mom2 + 2.f * mean * me2;
  const float m4c  = mom4 - 4.f * mean * mom3 + 6.f * me2 * mom2 - 3.f * me2 * me2;
  const float stdv = sqrtf(var + EPSF);
  const float s2   = stdv * stdv;
  const float skew = m3 / (s2 * stdv + EPSF);
  const float kurt = m4c / (s2 * s2 + EPSF) - 3.f;
  const float maxs = mx + logf(sx);        // TEMP = 1
  const float mins = -(mnv + logf(sn));
  const float neff = ne + EPSF;
  const float kap4 = m4c - 3.f * var * var;

  const float st[19] = {mean, var, stdv, skew, kurt, mins, maxs, neff,
                        mean, mom2, mom3, mom4, var, m3, m4c, mean, var, m3, kap4};
  float* o = out + (((size_t)b * Cn + (t >> 2)) * Kn + (t & 3)) * 19;
  #pragma unroll
  for (int j = 0; j < 19; ++j) {
    const float x = st[j];
    o[j] = isfinite(x) ? x : 0.f;          // nan_to_num(nan/inf -> 0)
  }
}

extern "C" void kernel_launch(void* const* d_in, const int* in_sizes, int n_in,
                              void* d_out, int out_size, void* d_ws, size_t ws_size,
                              hipStream_t stream) {
  const float* values  = (const float*)d_in[0];
  const float* mask    = (const float*)d_in[1];
  const float* weights = (const float*)d_in[2];
  float* out = (float*)d_out;
  float* ws  = (float*)d_ws;   // needs 512 * 640 * 4 B = 1.31 MB

  stats_partial<<<Bn * NSPLIT, 256, 0, stream>>>(values, mask, weights, ws);
  stats_final<<<Bn, 64, 0, stream>>>(ws, out);
}